// Round 6
// baseline (161.668 us; speedup 1.0000x reference)
//
#include <hip/hip_runtime.h>

// RelationGAT fused flash-attention, MFMA fp16 (gfx950) -- R13 "2-wave blocks, DMA-staged shared K/V".
// out = softmax((x@Wq^T+bq) @ (nb@Wk^T+bk)^T) @ nb @ Wv^T + bv
// bk cancels in softmax. Q~ = x@G + u, G = Wq^T Wk, u = bq^T Wk; K=V=raw nb.
//
// R13 theory: R9-R12 established ILP/TLP changes are null-to-negative; only
// memory-path reductions paid. Each wave privately pulls all 256KB of KF+VF
// through the VMEM path (800MB chip-wide). Fix: share the stream -- 2 waves/
// block, K/V staged per 64-key stage into double-buffered LDS (2x16KB) via
// global_load_lds (frag-major layout is exactly linear in lane order, the
// wave-uniform-base requirement; 8x 1KB DMA per wave per stage), compute reads
// conflict-free ds_read_b128. One __syncthreads per stage (2-phase pattern);
// prefetch issued at stage top has the whole ~2000cyc compute phase to land.
// Traffic halves; VMEM pipe sees DMA issues only (no register round-trip).
// R8's anti-staging lesson doesn't apply: no conversion VALU, no transpose
// scatter, no bank conflicts -- staging is pure DMA of pre-formatted frags.
// Setup slices alias LDS buf1 (first overwritten only after post-setup barrier);
// stage-0 DMA issued BEFORE setup so Q~ MFMAs hide its latency.
//
// Workspace layout (278784 B):
//   [0,8192)         GFh  fp16 frag-major G^T hi: [f=mt*2+ks][lane][8]
//   [8192,16384)     GFl  fp16 frag-major G^T lo
//   [16384,16640)    uW   f32 [64]
//   [16640,147712)   KF   fp16 [tile][f=t*2+h][lane][8], key-permuted
//   [147712,278784)  VF   fp16 [tile][dt][lane][8], natural key order

#define N_ROWS 100000
#define LOG2E 1.44269504088896f
#define GATE_THR 11.5424f   // 8 nats in log2 units; p <= 2^11.54 ~ 2981 fits fp16

typedef __attribute__((ext_vector_type(8))) _Float16 half8;
typedef __attribute__((ext_vector_type(4))) float    f32x4;

#define MFMA16(a,b,c) __builtin_amdgcn_mfma_f32_16x16x32_f16((a),(b),(c),0,0,0)
#define WAIT_LGKM0()  __builtin_amdgcn_s_waitcnt(0xc07f)   // lgkmcnt(0) only, vmcnt/expcnt untouched

static __device__ __forceinline__ f32x4 zero4() {
    f32x4 v = {0.f, 0.f, 0.f, 0.f};
    return v;
}

// async 16B/lane global->LDS DMA: per-lane global src, wave-uniform LDS dst (HW adds lane*16)
static __device__ __forceinline__ void gload16(const void* g, void* l) {
    __builtin_amdgcn_global_load_lds(
        (const __attribute__((address_space(1))) unsigned int*)g,
        (__attribute__((address_space(3))) unsigned int*)l, 16, 0, 0);
}

// ---------------- prep: GF hi/lo + u (block 0), nb -> KF/VF fp16 (blocks 1..16) ----------------
__global__ __launch_bounds__(256)
void prep_kernel(const float* __restrict__ nb, const float* __restrict__ Wq,
                 const float* __restrict__ bq, const float* __restrict__ Wk,
                 unsigned short* __restrict__ GFh, unsigned short* __restrict__ GFl,
                 float* __restrict__ uW, unsigned short* __restrict__ KF,
                 unsigned short* __restrict__ VF)
{
    __shared__ __align__(16) float sm[8192];   // 32KB: blk0 Wk|Wq, blks>0 transpose tile
    const int tid = threadIdx.x;
    if (blockIdx.x == 0) {
        const float4* wk4 = (const float4*)Wk;
        const float4* wq4 = (const float4*)Wq;
        float4* dk = (float4*)sm;
        float4* dq = (float4*)(sm + 4096);
        #pragma unroll
        for (int u = 0; u < 4; u++) {
            dk[u * 256 + tid] = wk4[u * 256 + tid];
            dq[u * 256 + tid] = wq4[u * 256 + tid];
        }
        __syncthreads();
        const int e2 = tid & 63, e1g = (tid >> 6) * 16;
        float g[16];
        #pragma unroll
        for (int q = 0; q < 16; q++) g[q] = 0.f;
        for (int w = 0; w < 64; w++) {
            float kv = sm[w * 64 + e2];
            const float* wqp = sm + 4096 + w * 64 + e1g;
            #pragma unroll
            for (int q = 0; q < 16; q++) g[q] = fmaf(wqp[q], kv, g[q]);
        }
        union { half8 h; uint4 u; } ph0, pl0, ph1, pl1;
        #pragma unroll
        for (int i = 0; i < 8; i++) {
            _Float16 h0 = (_Float16)g[i];
            ph0.h[i] = h0; pl0.h[i] = (_Float16)(g[i] - (float)h0);
            _Float16 h1 = (_Float16)g[8 + i];
            ph1.h[i] = h1; pl1.h[i] = (_Float16)(g[8 + i] - (float)h1);
        }
        // frag-major: f = mt*2+ks, lane = Q*16+c ; this thread owns row e2 ->
        // (mt = e2>>4, c = e2&15), cols e1g..e1g+15 -> ks = tid>>7, Q0 = 2*((tid>>6)&1)
        const int mt = e2 >> 4, cc = e2 & 15;
        const int ks = tid >> 7, Q0 = 2 * ((tid >> 6) & 1);
        const int f  = mt * 2 + ks;
        *(uint4*)(GFh + (f * 64 + Q0 * 16 + cc) * 8)       = ph0.u;
        *(uint4*)(GFh + (f * 64 + (Q0 + 1) * 16 + cc) * 8) = ph1.u;
        *(uint4*)(GFl + (f * 64 + Q0 * 16 + cc) * 8)       = pl0.u;
        *(uint4*)(GFl + (f * 64 + (Q0 + 1) * 16 + cc) * 8) = pl1.u;
        if (tid < 64) {
            float uu = 0.f;
            for (int w = 0; w < 64; w++) uu = fmaf(bq[w], sm[w * 64 + tid], uu);
            uW[tid] = uu;
        }
    } else {
        const int j0 = (blockIdx.x - 1) * 64;    // this block's 64 keys (2 tiles)
        const int T0 = (blockIdx.x - 1) * 2;
        // stage 64x64 f32 tile to LDS [64][65] for the VF transpose
        {
            const int jr = tid >> 2, c0 = (tid & 3) * 16;
            const float* np = nb + (size_t)(j0 + jr) * 64 + c0;
            #pragma unroll
            for (int u = 0; u < 4; u++) {
                float4 v = *(const float4*)(np + 4 * u);
                sm[jr * 65 + c0 + 4 * u]     = v.x;
                sm[jr * 65 + c0 + 4 * u + 1] = v.y;
                sm[jr * 65 + c0 + 4 * u + 2] = v.z;
                sm[jr * 65 + c0 + 4 * u + 3] = v.w;
            }
        }
        // KF direct from global: slot -> (tt, f=(t,h), lane=(Q,c)); stored key row is the
        // PERMUTED key keyof(t,c) so that S-frag reg r at lane(Q,c) = key 8Q+4t+r.
        #pragma unroll
        for (int s = 0; s < 2; s++) {
            const int slot = tid + 256 * s;
            const int tt = (slot >> 8) & 1, f = (slot >> 6) & 3, ln = slot & 63;
            const int t = f >> 1, h = f & 1, Qw = ln >> 4, cw = ln & 15;
            const int key = ((cw >> 3) & 1) * 16 + ((cw >> 2) & 1) * 8 + 4 * t + (cw & 3);
            const float* kp = nb + (size_t)((T0 + tt) * 32 + key) * 64 + h * 32 + Qw * 8;
            float b[8];
            *(float4*)b       = *(const float4*)kp;
            *(float4*)(b + 4) = *(const float4*)(kp + 4);
            union { half8 hh; uint4 u; } pk;
            #pragma unroll
            for (int i = 0; i < 8; i++) pk.hh[i] = (_Float16)b[i];
            *(uint4*)(KF + (size_t)(T0 + tt) * 2048 + f * 512 + ln * 8) = pk.u;
        }
        __syncthreads();
        // VF from LDS transpose: vA[dt][i] = V^T[dt*16+c][T*32 + Q*8 + i] (natural order)
        #pragma unroll
        for (int s = 0; s < 2; s++) {
            const int slot = tid + 256 * s;
            const int tt = (slot >> 8) & 1, dt = (slot >> 6) & 3, ln = slot & 63;
            const int Qw = ln >> 4, cw = ln & 15;
            union { half8 hh; uint4 u; } pv;
            #pragma unroll
            for (int i = 0; i < 8; i++)
                pv.hh[i] = (_Float16)sm[(tt * 32 + Qw * 8 + i) * 65 + dt * 16 + cw];
            *(uint4*)(VF + (size_t)(T0 + tt) * 2048 + dt * 512 + ln * 8) = pv.u;
        }
    }
}

// ---------------- main: 2-wave blocks, 32 rows/wave, DMA-staged shared K/V ----------------
// LDS: buf0 [0,16384), buf1 [16384,32768). Per buffer: [0,4K) K-even tile,
// [4K,8K) K-odd, [8K,12K) V-even, [12K,16K) V-odd (frag-major, lane-linear).
// Setup Q-slices alias buf1 (dead before first buf1 prefetch lands).
__global__ __launch_bounds__(128, 2)
void attn_kernel(const float* __restrict__ x,
                 const unsigned short* __restrict__ GFh,
                 const unsigned short* __restrict__ GFl,
                 const float* __restrict__ uW,
                 const unsigned short* __restrict__ KF,
                 const unsigned short* __restrict__ VF,
                 const float* __restrict__ Wv,
                 const float* __restrict__ bv,
                 float* __restrict__ out)
{
    __shared__ __align__(16) char smem[32768];
    const int tid  = threadIdx.x;
    const int lane = tid & 63;
    const int wv   = tid >> 6;     // wave 0..1
    const int Q    = lane >> 4;    // quad 0..3
    const int c    = lane & 15;    // col 0..15
    const int rbase = blockIdx.x * 64 + wv * 32;   // this wave's 32 q-rows
    float* slice = (float*)(smem + 16384) + wv * 1088;   // [16][68] f32, aliases buf1

    // ---- stage 0 DMA first: latency hides under the Q~ setup MFMAs ----
    {
        const size_t tgl = (size_t)wv * 2048 + (size_t)lane * 8;   // tile wv (stage 0)
        char* dK = smem + wv * 4096;
        char* dV = smem + 8192 + wv * 4096;
        #pragma unroll
        for (int f = 0; f < 4; f++) {
            gload16(KF + tgl + f * 512, dK + f * 1024);
            gload16(VF + tgl + f * 512, dV + f * 1024);
        }
    }

    // ------- setup: Q~^T = G^T x^T via MFMA (frag-major G from L2) -> q-frags hi/lo -------
    // log2(e) folded into Q~ before the hi/lo split -> scores come out log2-scaled.
    half8 qh[2][2], ql[2][2];   // [rt][ks] -- static indices ONLY
    #pragma unroll
    for (int rt = 0; rt < 2; rt++) {
        int row = rbase + rt * 16 + c;
        if (row > N_ROWS - 1) row = N_ROWS - 1;   // tail block: clamp (dup compute, guarded store)
        half8 xh[2], xl[2];
        #pragma unroll
        for (int ks = 0; ks < 2; ks++) {
            const float* xp = x + (size_t)row * 64 + ks * 32 + Q * 8;
            float a[8];
            *(float4*)a       = *(const float4*)xp;
            *(float4*)(a + 4) = *(const float4*)(xp + 4);
            #pragma unroll
            for (int i = 0; i < 8; i++) {
                _Float16 h = (_Float16)a[i];
                xh[ks][i] = h;
                xl[ks][i] = (_Float16)(a[i] - (float)h);
            }
        }
        #pragma unroll
        for (int mt = 0; mt < 4; mt++) {
            f32x4 Cm = zero4();
            #pragma unroll
            for (int ks = 0; ks < 2; ks++) {
                half8 gh = *(const half8*)(GFh + ((mt * 2 + ks) * 64 + lane) * 8);
                half8 gl = *(const half8*)(GFl + ((mt * 2 + ks) * 64 + lane) * 8);
                Cm = MFMA16(gh, xh[ks], Cm);   // D[dout][x-row]
                Cm = MFMA16(gh, xl[ks], Cm);
                Cm = MFMA16(gl, xh[ks], Cm);
            }
            // C row = dout mt*16+4Q+r, col = x-row c -> slice[x-row][dout]
            *(f32x4*)(slice + c * 68 + mt * 16 + 4 * Q) = Cm;
        }
        WAIT_LGKM0();   // wave-local LDS RAW (slice is wave-private); don't drain stage-0 DMA
        #pragma unroll
        for (int ks = 0; ks < 2; ks++) {
            const float* qp = slice + c * 68 + ks * 32 + Q * 8;
            const float* up = uW + ks * 32 + Q * 8;
            #pragma unroll
            for (int i = 0; i < 8; i++) {
                float val = (qp[i] + up[i]) * LOG2E;
                _Float16 h = (_Float16)val;
                qh[rt][ks][i] = h;
                ql[rt][ks][i] = (_Float16)(val - (float)h);
            }
        }
        WAIT_LGKM0();   // reads done before rt=1 overwrites slice
    }
    __syncthreads();   // stage-0 DMA landed (vmcnt drain) + both waves done with slices

    // -------- flash loop: 16 stages x 64 keys (tiles 2t,2t+1), shared LDS K/V --------
    f32x4 acc[2][4];   // [qt][dt] agg^T C-frags (static idx only)
    #pragma unroll
    for (int qt = 0; qt < 2; qt++)
        #pragma unroll
        for (int dt = 0; dt < 4; dt++) acc[qt][dt] = zero4();
    float mrow[2] = { -3.0e38f, -3.0e38f };
    float lrow[2] = { 0.f, 0.f };

    #pragma unroll 1
    for (int TT = 0; TT < 16; TT++) {
        // ---- issue next stage's DMA into the other buffer (full stage to land) ----
        if (TT < 15) {
            const size_t tgl = (size_t)(2 * (TT + 1) + wv) * 2048 + (size_t)lane * 8;
            char* base = smem + ((TT + 1) & 1) * 16384;
            char* dK = base + wv * 4096;
            char* dV = base + 8192 + wv * 4096;
            #pragma unroll
            for (int f = 0; f < 4; f++) {
                gload16(KF + tgl + f * 512, dK + f * 1024);
                gload16(VF + tgl + f * 512, dV + f * 1024);
            }
        }
        // ---- conflict-free ds_read of this stage's 16 frags ----
        const char* rb = smem + (TT & 1) * 16384;
        half8 kA[4], kB[4], vA[4], vB[4];
        #pragma unroll
        for (int f = 0; f < 4; f++) {
            kA[f] = *(const half8*)(rb + f * 1024 + lane * 16);
            kB[f] = *(const half8*)(rb + 4096 + f * 1024 + lane * 16);
            vA[f] = *(const half8*)(rb + 8192 + f * 1024 + lane * 16);
            vB[f] = *(const half8*)(rb + 12288 + f * 1024 + lane * 16);
        }

        // ---- 32 QK MFMAs, branch-free: 8 independent 4-deep chains ----
        f32x4 Sa[2][2], Sb[2][2];   // [t][qt], log2-scaled scores
        #pragma unroll
        for (int t = 0; t < 2; t++)
            #pragma unroll
            for (int qt = 0; qt < 2; qt++) {
                f32x4 s = MFMA16(kA[2 * t],     qh[qt][0], zero4());
                s = MFMA16(kA[2 * t + 1], qh[qt][1], s);
                s = MFMA16(kA[2 * t],     ql[qt][0], s);
                s = MFMA16(kA[2 * t + 1], ql[qt][1], s);
                Sa[t][qt] = s;
                f32x4 u = MFMA16(kB[2 * t],     qh[qt][0], zero4());
                u = MFMA16(kB[2 * t + 1], qh[qt][1], u);
                u = MFMA16(kB[2 * t],     ql[qt][0], u);
                u = MFMA16(kB[2 * t + 1], ql[qt][1], u);
                Sb[t][qt] = u;
            }

        // ---- ONE defer-max gate for all 64 keys, both qt (union gate, rare) ----
        float pmax[2];
        #pragma unroll
        for (int qt = 0; qt < 2; qt++) {
            float ma = fmaxf(fmaxf(fmaxf(Sa[0][qt][0], Sa[0][qt][1]),
                                   fmaxf(Sa[0][qt][2], Sa[0][qt][3])),
                             fmaxf(fmaxf(Sa[1][qt][0], Sa[1][qt][1]),
                                   fmaxf(Sa[1][qt][2], Sa[1][qt][3])));
            float mb = fmaxf(fmaxf(fmaxf(Sb[0][qt][0], Sb[0][qt][1]),
                                   fmaxf(Sb[0][qt][2], Sb[0][qt][3])),
                             fmaxf(fmaxf(Sb[1][qt][0], Sb[1][qt][1]),
                                   fmaxf(Sb[1][qt][2], Sb[1][qt][3])));
            pmax[qt] = fmaxf(ma, mb);
        }
        if (__any((pmax[0] > mrow[0] + GATE_THR) | (pmax[1] > mrow[1] + GATE_THR))) {
            #pragma unroll
            for (int qt = 0; qt < 2; qt++) {
                float cm = pmax[qt];
                cm = fmaxf(cm, __shfl_xor(cm, 16));
                cm = fmaxf(cm, __shfl_xor(cm, 32));   // uniform per q-row c across quads
                const float mn = fmaxf(mrow[qt], cm);
                const float sc = __builtin_amdgcn_exp2f(mrow[qt] - mn);
                mrow[qt] = mn;
                lrow[qt] *= sc;
                #pragma unroll
                for (int dt = 0; dt < 4; dt++)
                    #pragma unroll
                    for (int r = 0; r < 4; r++) acc[qt][dt][r] *= sc;
            }
        }

        // ---- 32 exps + packs (2 independent chains), then 16 PV MFMAs ----
        half8 pBa[2], pBb[2];
        #pragma unroll
        for (int qt = 0; qt < 2; qt++) {
            const float mref = mrow[qt];
            float ps = 0.f;
            float pa[8], pb[8];
            #pragma unroll
            for (int r = 0; r < 4; r++) {
                pa[r]     = __builtin_amdgcn_exp2f(Sa[0][qt][r] - mref);
                pa[4 + r] = __builtin_amdgcn_exp2f(Sa[1][qt][r] - mref);
                pb[r]     = __builtin_amdgcn_exp2f(Sb[0][qt][r] - mref);
                pb[4 + r] = __builtin_amdgcn_exp2f(Sb[1][qt][r] - mref);
            }
            #pragma unroll
            for (int i = 0; i < 8; i++) { ps += pa[i]; ps += pb[i]; }
            lrow[qt] += ps;   // per-lane PARTIAL (this lane's 16 keys); reduced in epilogue
            #pragma unroll
            for (int i = 0; i < 8; i++) {
                pBa[qt][i] = (_Float16)pa[i];   // S C-frag matches PV B-frag
                pBb[qt][i] = (_Float16)pb[i];
            }
        }
        #pragma unroll
        for (int dt = 0; dt < 4; dt++) {
            acc[0][dt] = MFMA16(vA[dt], pBa[0], acc[0][dt]);
            acc[1][dt] = MFMA16(vA[dt], pBa[1], acc[1][dt]);
            acc[0][dt] = MFMA16(vB[dt], pBb[0], acc[0][dt]);
            acc[1][dt] = MFMA16(vB[dt], pBb[1], acc[1][dt]);
        }
        // one barrier per stage: compiler emits vmcnt(0) lgkmcnt(0) drain first,
        // which guarantees (a) this stage's ds_reads done before partner's next
        // DMA overwrites this buffer, (b) next buffer's DMA landed.
        __syncthreads();
    }

    // ---------------- epilogue: reduce lrow partials, out = (agg/l) @ Wv^T + bv ----------------
    #pragma unroll
    for (int qt = 0; qt < 2; qt++) {
        float l = lrow[qt];
        l += __shfl_xor(l, 16);
        l += __shfl_xor(l, 32);     // once per kernel, not per iter
        const float rl = 1.f / l;
        #pragma unroll
        for (int dt = 0; dt < 4; dt++)
            #pragma unroll
            for (int r = 0; r < 4; r++) acc[qt][dt][r] *= rl;
    }
    half8 wf[4][2];
    #pragma unroll
    for (int mt = 0; mt < 4; mt++)
        #pragma unroll
        for (int ks = 0; ks < 2; ks++) {
            const float* wp = Wv + (size_t)(mt * 16 + c) * 64 + ks * 32 + Q * 8;
            #pragma unroll
            for (int i = 0; i < 8; i++) wf[mt][ks][i] = (_Float16)wp[i];
        }
    const int srcA = 32 * (Q & 1) + c;
    const int srcB = srcA + 16;
    const bool hi = (Q >> 1) & 1;
    f32x4 o[2][4];
    #pragma unroll
    for (int qt = 0; qt < 2; qt++) {
        half8 pe[2];
        #pragma unroll
        for (int ks = 0; ks < 2; ks++) {
            #pragma unroll
            for (int r = 0; r < 4; r++) {
                float a0 = __shfl(acc[qt][2 * ks + 0][r], srcA);
                float a1 = __shfl(acc[qt][2 * ks + 1][r], srcA);
                float b0 = __shfl(acc[qt][2 * ks + 0][r], srcB);
                float b1 = __shfl(acc[qt][2 * ks + 1][r], srcB);
                pe[ks][r]     = (_Float16)(hi ? a1 : a0);
                pe[ks][4 + r] = (_Float16)(hi ? b1 : b0);
            }
        }
        #pragma unroll
        for (int mt = 0; mt < 4; mt++) {
            f32x4 t = MFMA16(wf[mt][0], pe[0], zero4());
            o[qt][mt] = MFMA16(wf[mt][1], pe[1], t);
        }
    }
    #pragma unroll
    for (int qt = 0; qt < 2; qt++) {
        const int row = rbase + qt * 16 + c;
        if (row < N_ROWS) {   // tail block: clamped rows don't store
            #pragma unroll
            for (int mt = 0; mt < 4; mt++) {
                const float4 bf = *(const float4*)(bv + mt * 16 + 4 * Q);
                float4 vv = make_float4(o[qt][mt][0] + bf.x, o[qt][mt][1] + bf.y,
                                        o[qt][mt][2] + bf.z, o[qt][mt][3] + bf.w);
                *(float4*)(out + (size_t)row * 64 + mt * 16 + 4 * Q) = vv;
            }
        }
    }
}

extern "C" void kernel_launch(void* const* d_in, const int* in_sizes, int n_in,
                              void* d_out, int out_size, void* d_ws, size_t ws_size,
                              hipStream_t stream)
{
    const float* x  = (const float*)d_in[0];
    const float* nb = (const float*)d_in[1];
    const float* Wq = (const float*)d_in[2];
    const float* bq = (const float*)d_in[3];
    const float* Wk = (const float*)d_in[4];
    // d_in[5] = bk: provably cancels in softmax -> unused
    const float* Wv = (const float*)d_in[6];
    const float* bv = (const float*)d_in[7];
    float* out = (float*)d_out;

    char* ws = (char*)d_ws;                                  // needs 278784 B
    unsigned short* GFh = (unsigned short*)(ws);             // 8192 B
    unsigned short* GFl = (unsigned short*)(ws + 8192);      // 8192 B
    float*          uW  = (float*)(ws + 16384);              // 256 B
    unsigned short* KF  = (unsigned short*)(ws + 16640);     // 131072 B
    unsigned short* VF  = (unsigned short*)(ws + 147712);    // 131072 B (end 278784)

    prep_kernel<<<17, 256, 0, stream>>>(nb, Wq, bq, Wk, GFh, GFl, uW, KF, VF);
    const int grid = (N_ROWS + 63) / 64;   // 1563 2-wave blocks, 64 rows each
    attn_kernel<<<grid, 128, 0, stream>>>(x, GFh, GFl, uW, KF, VF, Wv, bv, out);
}

// Round 8
// 152.416 us; speedup vs baseline: 1.0607x; 1.0607x over previous
//
#include <hip/hip_runtime.h>

// RelationGAT fused flash-attention, MFMA fp16 (gfx950) -- R14b "cross-step pipeline (T15)".
// (R14 failed to COMPILE: cvt_pkrtz returns __fp16 ext_vector(2), not _Float16
//  ext_vector(2). Fixed via __fp16-typed union member -- layout-identical pun,
//  zero codegen change. Theory/predictions unchanged from R14.)
// out = softmax((x@Wq^T+bq) @ (nb@Wk^T+bk)^T) @ nb @ Wv^T + bv
// bk cancels in softmax. Q~ = x@G + u, G = Wq^T Wk, u = bq^T Wk; K=V=raw nb.
//
// R14 theory: R8-R13 swept staging/TLP/traffic/ILP-width; time stayed 74-96us,
// insensitive to occupancy (13-32%) and traffic (400-1600MB); both pipes <25%
// utilized. Per-wave wall ~2900cyc/step vs ~650cyc issue -> the cost is the
// serial per-tile chain QK-MFMA -> hazard -> fmax -> exp -> pack -> PV, never
// restructured. Fix (T15 att[2] double-pipeline): iteration T issues QK of tile
// T+1 FIRST (independent MFMA), then softmax of tile T (its S has a full iter
// of latency slack), then PV of tile T. S ping-pongs through two named buffers
// (static idx only). K reloaded in-place right after QK consumes it (~3/4-iter
// slack); V in-place after PV. Bundled: cvt_pkrtz packs p-pairs f32->fp16 in
// one instr (~-16 instr/step; RTZ on fp16 weights is <=2^-11 relative).
// Keeps R10 operating point: 1-wave blocks, 32 rows, grid 3125, frag-major
// direct-L2 loads, exp2 domain, defer-max gate. VGPR ~155, bounds (64,3).
//
// Workspace layout (278784 B):
//   [0,8192)         GFh  fp16 frag-major G^T hi: [f=mt*2+ks][lane][8]
//   [8192,16384)     GFl  fp16 frag-major G^T lo
//   [16384,16640)    uW   f32 [64]
//   [16640,147712)   KF   fp16 [tile][f=t*2+h][lane][8], key-permuted
//   [147712,278784)  VF   fp16 [tile][dt][lane][8], natural key order

#define N_ROWS 100000
#define LOG2E 1.44269504088896f
#define GATE_THR 11.5424f   // 8 nats in log2 units; p <= 2^11.54 ~ 2981 fits fp16

typedef __attribute__((ext_vector_type(8))) _Float16 half8;
typedef __attribute__((ext_vector_type(2))) __fp16   fp16x2;   // cvt_pkrtz return type
typedef __attribute__((ext_vector_type(4))) float    f32x4;

#define MFMA16(a,b,c) __builtin_amdgcn_mfma_f32_16x16x32_f16((a),(b),(c),0,0,0)

static __device__ __forceinline__ f32x4 zero4() {
    f32x4 v = {0.f, 0.f, 0.f, 0.f};
    return v;
}

// ---------------- prep: GF hi/lo + u (block 0), nb -> KF/VF fp16 (blocks 1..16) ----------------
__global__ __launch_bounds__(256)
void prep_kernel(const float* __restrict__ nb, const float* __restrict__ Wq,
                 const float* __restrict__ bq, const float* __restrict__ Wk,
                 unsigned short* __restrict__ GFh, unsigned short* __restrict__ GFl,
                 float* __restrict__ uW, unsigned short* __restrict__ KF,
                 unsigned short* __restrict__ VF)
{
    __shared__ __align__(16) float sm[8192];   // 32KB: blk0 Wk|Wq, blks>0 transpose tile
    const int tid = threadIdx.x;
    if (blockIdx.x == 0) {
        const float4* wk4 = (const float4*)Wk;
        const float4* wq4 = (const float4*)Wq;
        float4* dk = (float4*)sm;
        float4* dq = (float4*)(sm + 4096);
        #pragma unroll
        for (int u = 0; u < 4; u++) {
            dk[u * 256 + tid] = wk4[u * 256 + tid];
            dq[u * 256 + tid] = wq4[u * 256 + tid];
        }
        __syncthreads();
        const int e2 = tid & 63, e1g = (tid >> 6) * 16;
        float g[16];
        #pragma unroll
        for (int q = 0; q < 16; q++) g[q] = 0.f;
        for (int w = 0; w < 64; w++) {
            float kv = sm[w * 64 + e2];
            const float* wqp = sm + 4096 + w * 64 + e1g;
            #pragma unroll
            for (int q = 0; q < 16; q++) g[q] = fmaf(wqp[q], kv, g[q]);
        }
        union { half8 h; uint4 u; } ph0, pl0, ph1, pl1;
        #pragma unroll
        for (int i = 0; i < 8; i++) {
            _Float16 h0 = (_Float16)g[i];
            ph0.h[i] = h0; pl0.h[i] = (_Float16)(g[i] - (float)h0);
            _Float16 h1 = (_Float16)g[8 + i];
            ph1.h[i] = h1; pl1.h[i] = (_Float16)(g[8 + i] - (float)h1);
        }
        // frag-major: f = mt*2+ks, lane = Q*16+c ; this thread owns row e2 ->
        // (mt = e2>>4, c = e2&15), cols e1g..e1g+15 -> ks = tid>>7, Q0 = 2*((tid>>6)&1)
        const int mt = e2 >> 4, cc = e2 & 15;
        const int ks = tid >> 7, Q0 = 2 * ((tid >> 6) & 1);
        const int f  = mt * 2 + ks;
        *(uint4*)(GFh + (f * 64 + Q0 * 16 + cc) * 8)       = ph0.u;
        *(uint4*)(GFh + (f * 64 + (Q0 + 1) * 16 + cc) * 8) = ph1.u;
        *(uint4*)(GFl + (f * 64 + Q0 * 16 + cc) * 8)       = pl0.u;
        *(uint4*)(GFl + (f * 64 + (Q0 + 1) * 16 + cc) * 8) = pl1.u;
        if (tid < 64) {
            float uu = 0.f;
            for (int w = 0; w < 64; w++) uu = fmaf(bq[w], sm[w * 64 + tid], uu);
            uW[tid] = uu;
        }
    } else {
        const int j0 = (blockIdx.x - 1) * 64;    // this block's 64 keys (2 tiles)
        const int T0 = (blockIdx.x - 1) * 2;
        // stage 64x64 f32 tile to LDS [64][65] for the VF transpose
        {
            const int jr = tid >> 2, c0 = (tid & 3) * 16;
            const float* np = nb + (size_t)(j0 + jr) * 64 + c0;
            #pragma unroll
            for (int u = 0; u < 4; u++) {
                float4 v = *(const float4*)(np + 4 * u);
                sm[jr * 65 + c0 + 4 * u]     = v.x;
                sm[jr * 65 + c0 + 4 * u + 1] = v.y;
                sm[jr * 65 + c0 + 4 * u + 2] = v.z;
                sm[jr * 65 + c0 + 4 * u + 3] = v.w;
            }
        }
        // KF direct from global: slot -> (tt, f=(t,h), lane=(Q,c)); stored key row is the
        // PERMUTED key keyof(t,c) so that S-frag reg r at lane(Q,c) = key 8Q+4t+r.
        #pragma unroll
        for (int s = 0; s < 2; s++) {
            const int slot = tid + 256 * s;
            const int tt = (slot >> 8) & 1, f = (slot >> 6) & 3, ln = slot & 63;
            const int t = f >> 1, h = f & 1, Qw = ln >> 4, cw = ln & 15;
            const int key = ((cw >> 3) & 1) * 16 + ((cw >> 2) & 1) * 8 + 4 * t + (cw & 3);
            const float* kp = nb + (size_t)((T0 + tt) * 32 + key) * 64 + h * 32 + Qw * 8;
            float b[8];
            *(float4*)b       = *(const float4*)kp;
            *(float4*)(b + 4) = *(const float4*)(kp + 4);
            union { half8 hh; uint4 u; } pk;
            #pragma unroll
            for (int i = 0; i < 8; i++) pk.hh[i] = (_Float16)b[i];
            *(uint4*)(KF + (size_t)(T0 + tt) * 2048 + f * 512 + ln * 8) = pk.u;
        }
        __syncthreads();
        // VF from LDS transpose: vA[dt][i] = V^T[dt*16+c][T*32 + Q*8 + i] (natural order)
        #pragma unroll
        for (int s = 0; s < 2; s++) {
            const int slot = tid + 256 * s;
            const int tt = (slot >> 8) & 1, dt = (slot >> 6) & 3, ln = slot & 63;
            const int Qw = ln >> 4, cw = ln & 15;
            union { half8 hh; uint4 u; } pv;
            #pragma unroll
            for (int i = 0; i < 8; i++)
                pv.hh[i] = (_Float16)sm[(tt * 32 + Qw * 8 + i) * 65 + dt * 16 + cw];
            *(uint4*)(VF + (size_t)(T0 + tt) * 2048 + dt * 512 + ln * 8) = pv.u;
        }
    }
}

// load one tile's 4 frags (contiguous 1KB per instr)
static __device__ __forceinline__ void load4(half8 (&dst)[4], const unsigned short* base) {
    #pragma unroll
    for (int f = 0; f < 4; f++) dst[f] = *(const half8*)(base + f * 512);
}

// QK^T for one 32-key tile: 16 MFMA, 8 independent 4-deep chains
static __device__ __forceinline__ void qk_tile(
    const half8 (&k)[4], const half8 (&qh)[2][2], const half8 (&ql)[2][2],
    f32x4 (&S)[2][2])
{
    #pragma unroll
    for (int t = 0; t < 2; t++)
        #pragma unroll
        for (int qt = 0; qt < 2; qt++) {
            f32x4 s = MFMA16(k[2 * t],     qh[qt][0], zero4());
            s = MFMA16(k[2 * t + 1], qh[qt][1], s);
            s = MFMA16(k[2 * t],     ql[qt][0], s);
            s = MFMA16(k[2 * t + 1], ql[qt][1], s);
            S[t][qt] = s;
        }
}

// softmax of one tile (S computed LAST iteration -> latency drained) + PV
static __device__ __forceinline__ void sm_pv(
    const f32x4 (&S)[2][2], const half8 (&vA)[4],
    f32x4 (&acc)[2][4], float (&mrow)[2], float (&lrow)[2])
{
    float pmax[2];
    #pragma unroll
    for (int qt = 0; qt < 2; qt++) {
        pmax[qt] = fmaxf(fmaxf(fmaxf(S[0][qt][0], S[0][qt][1]),
                               fmaxf(S[0][qt][2], S[0][qt][3])),
                         fmaxf(fmaxf(S[1][qt][0], S[1][qt][1]),
                               fmaxf(S[1][qt][2], S[1][qt][3])));
    }
    // defer-max (T13): wave-uniform gate via __any (VOPC+exec, zero DS ops)
    if (__any((pmax[0] > mrow[0] + GATE_THR) | (pmax[1] > mrow[1] + GATE_THR))) {
        #pragma unroll
        for (int qt = 0; qt < 2; qt++) {
            float cm = pmax[qt];
            cm = fmaxf(cm, __shfl_xor(cm, 16));
            cm = fmaxf(cm, __shfl_xor(cm, 32));   // uniform per q-row c across quads
            const float mn = fmaxf(mrow[qt], cm);
            const float sc = __builtin_amdgcn_exp2f(mrow[qt] - mn);
            mrow[qt] = mn;
            lrow[qt] *= sc;
            #pragma unroll
            for (int dt = 0; dt < 4; dt++)
                #pragma unroll
                for (int r = 0; r < 4; r++) acc[qt][dt][r] *= sc;
        }
    }
    union { half8 v; fp16x2 h2[4]; } pk[2];
    #pragma unroll
    for (int qt = 0; qt < 2; qt++) {
        const float mref = mrow[qt];
        float p[8]; float ps = 0.f;
        #pragma unroll
        for (int r = 0; r < 4; r++) {
            p[r]     = __builtin_amdgcn_exp2f(S[0][qt][r] - mref);
            p[4 + r] = __builtin_amdgcn_exp2f(S[1][qt][r] - mref);
        }
        #pragma unroll
        for (int i = 0; i < 8; i++) ps += p[i];
        lrow[qt] += ps;   // per-lane PARTIAL (this lane's 8 keys); reduced in epilogue
        // pack pairs f32->fp16 in one v_cvt_pkrtz each; order matches PV B-frag
        #pragma unroll
        for (int j = 0; j < 4; j++)
            pk[qt].h2[j] = __builtin_amdgcn_cvt_pkrtz(p[2 * j], p[2 * j + 1]);
    }
    #pragma unroll
    for (int dt = 0; dt < 4; dt++) {
        acc[0][dt] = MFMA16(vA[dt], pk[0].v, acc[0][dt]);
        acc[1][dt] = MFMA16(vA[dt], pk[1].v, acc[1][dt]);
    }
}

// ---------------- main: 1-wave blocks, 32 rows/wave, cross-step pipelined ----------------
__global__ __launch_bounds__(64, 3)
void attn_kernel(const float* __restrict__ x,
                 const unsigned short* __restrict__ GFh,
                 const unsigned short* __restrict__ GFl,
                 const float* __restrict__ uW,
                 const unsigned short* __restrict__ KF,
                 const unsigned short* __restrict__ VF,
                 const float* __restrict__ Wv,
                 const float* __restrict__ bv,
                 float* __restrict__ out)
{
    __shared__ __align__(16) float slice[1088];   // [16][68] f32 Q-transpose slice (wave-private)
    const int lane = threadIdx.x & 63;
    const int Q    = lane >> 4;    // quad 0..3
    const int c    = lane & 15;    // col 0..15
    const int rbase = blockIdx.x * 32;   // this wave's 32 q-rows (3125*32 = 100000 exactly)

    // ------- setup: Q~^T = G^T x^T via MFMA (frag-major G from L2) -> q-frags hi/lo -------
    // log2(e) folded into Q~ before the hi/lo split -> scores come out log2-scaled.
    half8 qh[2][2], ql[2][2];   // [rt][ks] -- static indices ONLY
    #pragma unroll
    for (int rt = 0; rt < 2; rt++) {
        const int row = rbase + rt * 16 + c;   // always < N_ROWS (exact tiling)
        half8 xh[2], xl[2];
        #pragma unroll
        for (int ks = 0; ks < 2; ks++) {
            const float* xp = x + (size_t)row * 64 + ks * 32 + Q * 8;
            float a[8];
            *(float4*)a       = *(const float4*)xp;
            *(float4*)(a + 4) = *(const float4*)(xp + 4);
            #pragma unroll
            for (int i = 0; i < 8; i++) {
                _Float16 h = (_Float16)a[i];
                xh[ks][i] = h;
                xl[ks][i] = (_Float16)(a[i] - (float)h);
            }
        }
        #pragma unroll
        for (int mt = 0; mt < 4; mt++) {
            f32x4 Cm = zero4();
            #pragma unroll
            for (int ks = 0; ks < 2; ks++) {
                half8 gh = *(const half8*)(GFh + ((mt * 2 + ks) * 64 + lane) * 8);
                half8 gl = *(const half8*)(GFl + ((mt * 2 + ks) * 64 + lane) * 8);
                Cm = MFMA16(gh, xh[ks], Cm);   // D[dout][x-row]
                Cm = MFMA16(gh, xl[ks], Cm);
                Cm = MFMA16(gl, xh[ks], Cm);
            }
            // C row = dout mt*16+4Q+r, col = x-row c -> slice[x-row][dout]
            *(f32x4*)(slice + c * 68 + mt * 16 + 4 * Q) = Cm;
        }
        __builtin_amdgcn_s_waitcnt(0);   // wave-local LDS RAW (slice is wave-private)
        #pragma unroll
        for (int ks = 0; ks < 2; ks++) {
            const float* qp = slice + c * 68 + ks * 32 + Q * 8;
            const float* up = uW + ks * 32 + Q * 8;
            #pragma unroll
            for (int i = 0; i < 8; i++) {
                float val = (qp[i] + up[i]) * LOG2E;
                _Float16 h = (_Float16)val;
                qh[rt][ks][i] = h;
                ql[rt][ks][i] = (_Float16)(val - (float)h);
            }
        }
        __builtin_amdgcn_s_waitcnt(0);   // reads done before rt=1 overwrites slice
    }

    // -------- pipelined flash loop: 32 tiles; iter T overlaps QK[T+1] with softmax/PV[T] --------
    f32x4 acc[2][4];
    #pragma unroll
    for (int qt = 0; qt < 2; qt++)
        #pragma unroll
        for (int dt = 0; dt < 4; dt++) acc[qt][dt] = zero4();
    float mrow[2] = { -3.0e38f, -3.0e38f };
    float lrow[2] = { 0.f, 0.f };

    const unsigned short* kfl = KF + lane * 8;   // per-lane frag base (ushort units)
    const unsigned short* vfl = VF + lane * 8;
    half8 kA[4], vA[4];
    f32x4 Sa[2][2], Sb[2][2];   // S ping-pong (static names, rule #20)

    // prologue: K0/V0 in, S0 computed, K1 in flight
    load4(kA, kfl);
    load4(vA, vfl);
    qk_tile(kA, qh, ql, Sa);         // S_0 (waits on K0)
    load4(kA, kfl + 2048);           // K_1

    #pragma unroll 1
    for (int TT = 0; TT < 16; TT++) {
        // ---- phase A: QK tile 2TT+1 (indep MFMA) || softmax+PV tile 2TT ----
        qk_tile(kA, qh, ql, Sb);                       // S_{2TT+1}
        {   int Tn = 2 * TT + 2; if (Tn > 31) Tn = 31;
            load4(kA, kfl + (size_t)Tn * 2048); }      // K_{2TT+2}, ~3/4-iter slack
        sm_pv(Sa, vA, acc, mrow, lrow);                // tile 2TT
        {   int Tn = 2 * TT + 1; if (Tn > 31) Tn = 31;
            load4(vA, vfl + (size_t)Tn * 2048); }      // V_{2TT+1}
        // ---- phase B: QK tile 2TT+2 || softmax+PV tile 2TT+1 ----
        qk_tile(kA, qh, ql, Sa);                       // S_{2TT+2} (TT=15: dup of 31, unused)
        {   int Tn = 2 * TT + 3; if (Tn > 31) Tn = 31;
            load4(kA, kfl + (size_t)Tn * 2048); }
        sm_pv(Sb, vA, acc, mrow, lrow);                // tile 2TT+1
        {   int Tn = 2 * TT + 2; if (Tn > 31) Tn = 31;
            load4(vA, vfl + (size_t)Tn * 2048); }
    }

    // ---------------- epilogue: reduce lrow partials, out = (agg/l) @ Wv^T + bv ----------------
    #pragma unroll
    for (int qt = 0; qt < 2; qt++) {
        float l = lrow[qt];
        l += __shfl_xor(l, 16);
        l += __shfl_xor(l, 32);     // once per kernel, not per iter
        const float rl = 1.f / l;
        #pragma unroll
        for (int dt = 0; dt < 4; dt++)
            #pragma unroll
            for (int r = 0; r < 4; r++) acc[qt][dt][r] *= rl;
    }
    half8 wf[4][2];
    #pragma unroll
    for (int mt = 0; mt < 4; mt++)
        #pragma unroll
        for (int ks = 0; ks < 2; ks++) {
            const float* wp = Wv + (size_t)(mt * 16 + c) * 64 + ks * 32 + Q * 8;
            #pragma unroll
            for (int i = 0; i < 8; i++) wf[mt][ks][i] = (_Float16)wp[i];
        }
    const int srcA = 32 * (Q & 1) + c;
    const int srcB = srcA + 16;
    const bool hi = (Q >> 1) & 1;
    f32x4 o[2][4];
    #pragma unroll
    for (int qt = 0; qt < 2; qt++) {
        half8 pe[2];
        #pragma unroll
        for (int ks = 0; ks < 2; ks++) {
            #pragma unroll
            for (int r = 0; r < 4; r++) {
                float a0 = __shfl(acc[qt][2 * ks + 0][r], srcA);
                float a1 = __shfl(acc[qt][2 * ks + 1][r], srcA);
                float b0 = __shfl(acc[qt][2 * ks + 0][r], srcB);
                float b1 = __shfl(acc[qt][2 * ks + 1][r], srcB);
                pe[ks][r]     = (_Float16)(hi ? a1 : a0);
                pe[ks][4 + r] = (_Float16)(hi ? b1 : b0);
            }
        }
        #pragma unroll
        for (int mt = 0; mt < 4; mt++) {
            f32x4 t = MFMA16(wf[mt][0], pe[0], zero4());
            o[qt][mt] = MFMA16(wf[mt][1], pe[1], t);
        }
    }
    #pragma unroll
    for (int qt = 0; qt < 2; qt++) {
        const int row = rbase + qt * 16 + c;   // always < N_ROWS (exact tiling)
        #pragma unroll
        for (int mt = 0; mt < 4; mt++) {
            const float4 bf = *(const float4*)(bv + mt * 16 + 4 * Q);
            float4 vv = make_float4(o[qt][mt][0] + bf.x, o[qt][mt][1] + bf.y,
                                    o[qt][mt][2] + bf.z, o[qt][mt][3] + bf.w);
            *(float4*)(out + (size_t)row * 64 + mt * 16 + 4 * Q) = vv;
        }
    }
}

extern "C" void kernel_launch(void* const* d_in, const int* in_sizes, int n_in,
                              void* d_out, int out_size, void* d_ws, size_t ws_size,
                              hipStream_t stream)
{
    const float* x  = (const float*)d_in[0];
    const float* nb = (const float*)d_in[1];
    const float* Wq = (const float*)d_in[2];
    const float* bq = (const float*)d_in[3];
    const float* Wk = (const float*)d_in[4];
    // d_in[5] = bk: provably cancels in softmax -> unused
    const float* Wv = (const float*)d_in[6];
    const float* bv = (const float*)d_in[7];
    float* out = (float*)d_out;

    char* ws = (char*)d_ws;                                  // needs 278784 B
    unsigned short* GFh = (unsigned short*)(ws);             // 8192 B
    unsigned short* GFl = (unsigned short*)(ws + 8192);      // 8192 B
    float*          uW  = (float*)(ws + 16384);              // 256 B
    unsigned short* KF  = (unsigned short*)(ws + 16640);     // 131072 B
    unsigned short* VF  = (unsigned short*)(ws + 147712);    // 131072 B (end 278784)

    prep_kernel<<<17, 256, 0, stream>>>(nb, Wq, bq, Wk, GFh, GFl, uW, KF, VF);
    const int grid = N_ROWS / 32;   // 3125 1-wave blocks, 32 rows each, zero padding
    attn_kernel<<<grid, 64, 0, stream>>>(x, GFh, GFl, uW, KF, VF, Wv, bv, out);
}

// Round 9
// 151.216 us; speedup vs baseline: 1.0691x; 1.0079x over previous
//
#include <hip/hip_runtime.h>

// RelationGAT fused flash-attention, MFMA fp16 (gfx950) -- R15 "64 q-rows/wave: halve loads/work".
// out = softmax((x@Wq^T+bq) @ (nb@Wk^T+bk)^T) @ nb @ Wv^T + bv
// bk cancels in softmax. Q~ = x@G + u, G = Wq^T Wk, u = bq^T Wk; K=V=raw nb.
//
// R15 theory: 8 experiments fit one law -- time tracks VMEM ops per unit work
// (R10 contiguous -14%; R11 2x loads/work +19%; R12 same loads null; R14b
// pipeline null). Per-wave arithmetic: 89k cyc / 256 loads = ~347 cyc/load ==
// L2 latency -> per-load exposed latency is the wall. Fix: 4 q-tiles per wave
// (64 rows/block, grid 1563): same 8 loads/step now cover 2x MFMA work (32 QK
// + 16 PV). Loads per work halve; each load has more covering compute. VGPR
// ~230, bounds (64,2) caps 256. Occupancy drops -- proven non-binding (R11/12).
// Per-qt epilogue keeps pressure flat. Bundled: prep widened to 33 blocks
// (32-key tiles); tree-sum for ps (kills a 16-deep serial add chain).
// Discriminating prediction: serialized-load theory -> 45-55us; additive-floor
// fit -> ~65. >=70us kills the law -> practical plateau, stop.
//
// Workspace layout (278784 B):
//   [0,8192)         GFh  fp16 frag-major G^T hi: [f=mt*2+ks][lane][8]
//   [8192,16384)     GFl  fp16 frag-major G^T lo
//   [16384,16640)    uW   f32 [64]
//   [16640,147712)   KF   fp16 [tile][f=t*2+h][lane][8], key-permuted
//   [147712,278784)  VF   fp16 [tile][dt][lane][8], natural key order

#define N_ROWS 100000
#define LOG2E 1.44269504088896f
#define GATE_THR 11.5424f   // 8 nats in log2 units; p <= 2^11.54 ~ 2981 fits fp16

typedef __attribute__((ext_vector_type(8))) _Float16 half8;
typedef __attribute__((ext_vector_type(2))) __fp16   fp16x2;   // cvt_pkrtz return type
typedef __attribute__((ext_vector_type(4))) float    f32x4;

#define MFMA16(a,b,c) __builtin_amdgcn_mfma_f32_16x16x32_f16((a),(b),(c),0,0,0)

static __device__ __forceinline__ f32x4 zero4() {
    f32x4 v = {0.f, 0.f, 0.f, 0.f};
    return v;
}

// ---------------- prep: GF hi/lo + u (block 0), nb -> KF/VF fp16 (blocks 1..32) ----------------
__global__ __launch_bounds__(256)
void prep_kernel(const float* __restrict__ nb, const float* __restrict__ Wq,
                 const float* __restrict__ bq, const float* __restrict__ Wk,
                 unsigned short* __restrict__ GFh, unsigned short* __restrict__ GFl,
                 float* __restrict__ uW, unsigned short* __restrict__ KF,
                 unsigned short* __restrict__ VF)
{
    __shared__ __align__(16) float sm[8192];   // 32KB: blk0 Wk|Wq, blks>0 transpose tile
    const int tid = threadIdx.x;
    if (blockIdx.x == 0) {
        const float4* wk4 = (const float4*)Wk;
        const float4* wq4 = (const float4*)Wq;
        float4* dk = (float4*)sm;
        float4* dq = (float4*)(sm + 4096);
        #pragma unroll
        for (int u = 0; u < 4; u++) {
            dk[u * 256 + tid] = wk4[u * 256 + tid];
            dq[u * 256 + tid] = wq4[u * 256 + tid];
        }
        __syncthreads();
        const int e2 = tid & 63, e1g = (tid >> 6) * 16;
        float g[16];
        #pragma unroll
        for (int q = 0; q < 16; q++) g[q] = 0.f;
        for (int w = 0; w < 64; w++) {
            float kv = sm[w * 64 + e2];
            const float* wqp = sm + 4096 + w * 64 + e1g;
            #pragma unroll
            for (int q = 0; q < 16; q++) g[q] = fmaf(wqp[q], kv, g[q]);
        }
        union { half8 h; uint4 u; } ph0, pl0, ph1, pl1;
        #pragma unroll
        for (int i = 0; i < 8; i++) {
            _Float16 h0 = (_Float16)g[i];
            ph0.h[i] = h0; pl0.h[i] = (_Float16)(g[i] - (float)h0);
            _Float16 h1 = (_Float16)g[8 + i];
            ph1.h[i] = h1; pl1.h[i] = (_Float16)(g[8 + i] - (float)h1);
        }
        // frag-major: f = mt*2+ks, lane = Q*16+c ; this thread owns row e2 ->
        // (mt = e2>>4, c = e2&15), cols e1g..e1g+15 -> ks = tid>>7, Q0 = 2*((tid>>6)&1)
        const int mt = e2 >> 4, cc = e2 & 15;
        const int ks = tid >> 7, Q0 = 2 * ((tid >> 6) & 1);
        const int f  = mt * 2 + ks;
        *(uint4*)(GFh + (f * 64 + Q0 * 16 + cc) * 8)       = ph0.u;
        *(uint4*)(GFh + (f * 64 + (Q0 + 1) * 16 + cc) * 8) = ph1.u;
        *(uint4*)(GFl + (f * 64 + Q0 * 16 + cc) * 8)       = pl0.u;
        *(uint4*)(GFl + (f * 64 + (Q0 + 1) * 16 + cc) * 8) = pl1.u;
        if (tid < 64) {
            float uu = 0.f;
            for (int w = 0; w < 64; w++) uu = fmaf(bq[w], sm[w * 64 + tid], uu);
            uW[tid] = uu;
        }
    } else {
        const int T0 = blockIdx.x - 1;   // this block's 32-key tile
        const int j0 = T0 * 32;
        // stage 32x64 f32 tile to LDS [32][65] for the VF transpose
        {
            const int jr = tid >> 3, c0 = (tid & 7) * 8;
            const float* np = nb + (size_t)(j0 + jr) * 64 + c0;
            float4 v0 = *(const float4*)np;
            float4 v1 = *(const float4*)(np + 4);
            sm[jr * 65 + c0 + 0] = v0.x; sm[jr * 65 + c0 + 1] = v0.y;
            sm[jr * 65 + c0 + 2] = v0.z; sm[jr * 65 + c0 + 3] = v0.w;
            sm[jr * 65 + c0 + 4] = v1.x; sm[jr * 65 + c0 + 5] = v1.y;
            sm[jr * 65 + c0 + 6] = v1.z; sm[jr * 65 + c0 + 7] = v1.w;
        }
        // KF direct from global: tid -> (f=(t,h), lane=(Q,c)); stored key row is the
        // PERMUTED key keyof(t,c) so that S-frag reg r at lane(Q,c) = key 8Q+4t+r.
        {
            const int f = tid >> 6, ln = tid & 63;
            const int t = f >> 1, h = f & 1, Qw = ln >> 4, cw = ln & 15;
            const int key = ((cw >> 3) & 1) * 16 + ((cw >> 2) & 1) * 8 + 4 * t + (cw & 3);
            const float* kp = nb + (size_t)(j0 + key) * 64 + h * 32 + Qw * 8;
            float b[8];
            *(float4*)b       = *(const float4*)kp;
            *(float4*)(b + 4) = *(const float4*)(kp + 4);
            union { half8 hh; uint4 u; } pk;
            #pragma unroll
            for (int i = 0; i < 8; i++) pk.hh[i] = (_Float16)b[i];
            *(uint4*)(KF + (size_t)T0 * 2048 + f * 512 + ln * 8) = pk.u;
        }
        __syncthreads();
        // VF from LDS transpose: VF[T0][dt][lane(Q,c)][i] = nb[j0 + Q*8 + i][dt*16+c]
        {
            const int dt = tid >> 6, ln = tid & 63;
            const int Qw = ln >> 4, cw = ln & 15;
            union { half8 hh; uint4 u; } pv;
            #pragma unroll
            for (int i = 0; i < 8; i++)
                pv.hh[i] = (_Float16)sm[(Qw * 8 + i) * 65 + dt * 16 + cw];
            *(uint4*)(VF + (size_t)T0 * 2048 + dt * 512 + ln * 8) = pv.u;
        }
    }
}

// load one tile's 4 frags (contiguous 1KB per instr)
static __device__ __forceinline__ void load4(half8 (&dst)[4], const unsigned short* base) {
    #pragma unroll
    for (int f = 0; f < 4; f++) dst[f] = *(const half8*)(base + f * 512);
}

// ---------------- main: 1-wave blocks, 64 rows/wave (4 q-tiles), frag-major K/V ----------------
__global__ __launch_bounds__(64, 2)
void attn_kernel(const float* __restrict__ x,
                 const unsigned short* __restrict__ GFh,
                 const unsigned short* __restrict__ GFl,
                 const float* __restrict__ uW,
                 const unsigned short* __restrict__ KF,
                 const unsigned short* __restrict__ VF,
                 const float* __restrict__ Wv,
                 const float* __restrict__ bv,
                 float* __restrict__ out)
{
    __shared__ __align__(16) float slice[1088];   // [16][68] f32 Q-transpose slice (wave-private)
    const int lane = threadIdx.x & 63;
    const int Q    = lane >> 4;    // quad 0..3
    const int c    = lane & 15;    // col 0..15
    const int rbase = blockIdx.x * 64;   // this wave's 64 q-rows (1562 full + 1 half-tail block)

    // ------- setup: Q~^T = G^T x^T via MFMA (frag-major G from L2) -> q-frags hi/lo -------
    // log2(e) folded into Q~ before the hi/lo split -> scores come out log2-scaled.
    half8 qh[4][2], ql[4][2];   // [rt][ks] -- static indices ONLY
    #pragma unroll
    for (int rt = 0; rt < 4; rt++) {
        int row = rbase + rt * 16 + c;
        if (row > N_ROWS - 1) row = N_ROWS - 1;   // tail block: clamp (dup compute, guarded store)
        half8 xh[2], xl[2];
        #pragma unroll
        for (int ks = 0; ks < 2; ks++) {
            const float* xp = x + (size_t)row * 64 + ks * 32 + Q * 8;
            float a[8];
            *(float4*)a       = *(const float4*)xp;
            *(float4*)(a + 4) = *(const float4*)(xp + 4);
            #pragma unroll
            for (int i = 0; i < 8; i++) {
                _Float16 h = (_Float16)a[i];
                xh[ks][i] = h;
                xl[ks][i] = (_Float16)(a[i] - (float)h);
            }
        }
        #pragma unroll
        for (int mt = 0; mt < 4; mt++) {
            f32x4 Cm = zero4();
            #pragma unroll
            for (int ks = 0; ks < 2; ks++) {
                half8 gh = *(const half8*)(GFh + ((mt * 2 + ks) * 64 + lane) * 8);
                half8 gl = *(const half8*)(GFl + ((mt * 2 + ks) * 64 + lane) * 8);
                Cm = MFMA16(gh, xh[ks], Cm);   // D[dout][x-row]
                Cm = MFMA16(gh, xl[ks], Cm);
                Cm = MFMA16(gl, xh[ks], Cm);
            }
            // C row = dout mt*16+4Q+r, col = x-row c -> slice[x-row][dout]
            *(f32x4*)(slice + c * 68 + mt * 16 + 4 * Q) = Cm;
        }
        __builtin_amdgcn_s_waitcnt(0);   // wave-local LDS RAW (slice is wave-private)
        #pragma unroll
        for (int ks = 0; ks < 2; ks++) {
            const float* qp = slice + c * 68 + ks * 32 + Q * 8;
            const float* up = uW + ks * 32 + Q * 8;
            #pragma unroll
            for (int i = 0; i < 8; i++) {
                float val = (qp[i] + up[i]) * LOG2E;
                _Float16 h = (_Float16)val;
                qh[rt][ks][i] = h;
                ql[rt][ks][i] = (_Float16)(val - (float)h);
            }
        }
        __builtin_amdgcn_s_waitcnt(0);   // reads done before next rt overwrites slice
    }

    // -------- flash loop: 32 tiles of 32 keys; 8 loads/step now cover 2x MFMA work --------
    f32x4 acc[4][4];   // [qt][dt] agg^T C-frags (static idx only)
    #pragma unroll
    for (int qt = 0; qt < 4; qt++)
        #pragma unroll
        for (int dt = 0; dt < 4; dt++) acc[qt][dt] = zero4();
    float mrow[4] = { -3.0e38f, -3.0e38f, -3.0e38f, -3.0e38f };
    float lrow[4] = { 0.f, 0.f, 0.f, 0.f };

    const unsigned short* kfl = KF + lane * 8;   // per-lane frag base (ushort units)
    const unsigned short* vfl = VF + lane * 8;
    half8 kA[4], vA[4];
    load4(kA, kfl);   // tile 0 K
    load4(vA, vfl);   // tile 0 V

    #pragma unroll 1
    for (int TT = 0; TT < 32; TT++) {
        const int Tn = (TT < 31) ? TT + 1 : 31;   // next tile (last reload redundant)

        // ---- 32 QK MFMAs: 16 independent 4-deep chains across 4 q-tiles ----
        f32x4 S[2][4];   // [t][qt], log2-scaled scores
        #pragma unroll
        for (int t = 0; t < 2; t++)
            #pragma unroll
            for (int qt = 0; qt < 4; qt++) {
                f32x4 s = MFMA16(kA[2 * t],     qh[qt][0], zero4());
                s = MFMA16(kA[2 * t + 1], qh[qt][1], s);
                s = MFMA16(kA[2 * t],     ql[qt][0], s);
                s = MFMA16(kA[2 * t + 1], ql[qt][1], s);
                S[t][qt] = s;
            }
        // ---- reload K in place (WAR after QK issue; softmax+PV covers latency) ----
        load4(kA, kfl + (size_t)Tn * 2048);

        // ---- ONE defer-max gate for all 4 q-tiles (union gate, rare) ----
        float pmax[4];
        #pragma unroll
        for (int qt = 0; qt < 4; qt++) {
            pmax[qt] = fmaxf(fmaxf(fmaxf(S[0][qt][0], S[0][qt][1]),
                                   fmaxf(S[0][qt][2], S[0][qt][3])),
                             fmaxf(fmaxf(S[1][qt][0], S[1][qt][1]),
                                   fmaxf(S[1][qt][2], S[1][qt][3])));
        }
        const bool need = (pmax[0] > mrow[0] + GATE_THR) | (pmax[1] > mrow[1] + GATE_THR) |
                          (pmax[2] > mrow[2] + GATE_THR) | (pmax[3] > mrow[3] + GATE_THR);
        if (__any(need)) {
            #pragma unroll
            for (int qt = 0; qt < 4; qt++) {
                float cm = pmax[qt];
                cm = fmaxf(cm, __shfl_xor(cm, 16));
                cm = fmaxf(cm, __shfl_xor(cm, 32));   // uniform per q-row c across quads
                const float mn = fmaxf(mrow[qt], cm);
                const float sc = __builtin_amdgcn_exp2f(mrow[qt] - mn);
                mrow[qt] = mn;
                lrow[qt] *= sc;
                #pragma unroll
                for (int dt = 0; dt < 4; dt++)
                    #pragma unroll
                    for (int r = 0; r < 4; r++) acc[qt][dt][r] *= sc;
            }
        }

        // ---- 32 exps + packs (4 independent chains), then 16 PV MFMAs ----
        union { half8 v; fp16x2 h2[4]; } pB[4];
        #pragma unroll
        for (int qt = 0; qt < 4; qt++) {
            const float mref = mrow[qt];
            float p[8];
            #pragma unroll
            for (int r = 0; r < 4; r++) {
                p[r]     = __builtin_amdgcn_exp2f(S[0][qt][r] - mref);
                p[4 + r] = __builtin_amdgcn_exp2f(S[1][qt][r] - mref);
            }
            // tree sum (depth 3, not a serial 8-chain)
            lrow[qt] += ((p[0] + p[1]) + (p[2] + p[3])) + ((p[4] + p[5]) + (p[6] + p[7]));
            // pack pairs f32->fp16 in one v_cvt_pkrtz each; order matches PV B-frag
            #pragma unroll
            for (int j = 0; j < 4; j++)
                pB[qt].h2[j] = __builtin_amdgcn_cvt_pkrtz(p[2 * j], p[2 * j + 1]);
        }
        #pragma unroll
        for (int dt = 0; dt < 4; dt++) {
            acc[0][dt] = MFMA16(vA[dt], pB[0].v, acc[0][dt]);
            acc[1][dt] = MFMA16(vA[dt], pB[1].v, acc[1][dt]);
            acc[2][dt] = MFMA16(vA[dt], pB[2].v, acc[2][dt]);
            acc[3][dt] = MFMA16(vA[dt], pB[3].v, acc[3][dt]);
        }
        // ---- reload V in place (WAR after PV issue; next QK+softmax covers latency) ----
        load4(vA, vfl + (size_t)Tn * 2048);
    }

    // ---------------- epilogue (per-qt to keep VGPR flat): out = (agg/l) @ Wv^T + bv ----------------
    half8 wf[4][2];
    #pragma unroll
    for (int mt = 0; mt < 4; mt++)
        #pragma unroll
        for (int ks = 0; ks < 2; ks++) {
            const float* wp = Wv + (size_t)(mt * 16 + c) * 64 + ks * 32 + Q * 8;
            #pragma unroll
            for (int i = 0; i < 8; i++) wf[mt][ks][i] = (_Float16)wp[i];
        }
    const int srcA = 32 * (Q & 1) + c;
    const int srcB = srcA + 16;
    const bool hi = (Q >> 1) & 1;
    #pragma unroll
    for (int qt = 0; qt < 4; qt++) {
        float l = lrow[qt];
        l += __shfl_xor(l, 16);
        l += __shfl_xor(l, 32);     // once per q-tile per kernel, not per iter
        const float rl = 1.f / l;
        #pragma unroll
        for (int dt = 0; dt < 4; dt++)
            #pragma unroll
            for (int r = 0; r < 4; r++) acc[qt][dt][r] *= rl;
        half8 pe[2];
        #pragma unroll
        for (int ks = 0; ks < 2; ks++) {
            #pragma unroll
            for (int r = 0; r < 4; r++) {
                float a0 = __shfl(acc[qt][2 * ks + 0][r], srcA);
                float a1 = __shfl(acc[qt][2 * ks + 1][r], srcA);
                float b0 = __shfl(acc[qt][2 * ks + 0][r], srcB);
                float b1 = __shfl(acc[qt][2 * ks + 1][r], srcB);
                pe[ks][r]     = (_Float16)(hi ? a1 : a0);
                pe[ks][4 + r] = (_Float16)(hi ? b1 : b0);
            }
        }
        const int row = rbase + qt * 16 + c;
        if (row < N_ROWS) {   // tail block: clamped rows don't store
            #pragma unroll
            for (int mt = 0; mt < 4; mt++) {
                f32x4 t = MFMA16(wf[mt][0], pe[0], zero4());
                f32x4 o = MFMA16(wf[mt][1], pe[1], t);
                const float4 bf = *(const float4*)(bv + mt * 16 + 4 * Q);
                float4 vv = make_float4(o[0] + bf.x, o[1] + bf.y,
                                        o[2] + bf.z, o[3] + bf.w);
                *(float4*)(out + (size_t)row * 64 + mt * 16 + 4 * Q) = vv;
            }
        }
    }
}

extern "C" void kernel_launch(void* const* d_in, const int* in_sizes, int n_in,
                              void* d_out, int out_size, void* d_ws, size_t ws_size,
                              hipStream_t stream)
{
    const float* x  = (const float*)d_in[0];
    const float* nb = (const float*)d_in[1];
    const float* Wq = (const float*)d_in[2];
    const float* bq = (const float*)d_in[3];
    const float* Wk = (const float*)d_in[4];
    // d_in[5] = bk: provably cancels in softmax -> unused
    const float* Wv = (const float*)d_in[6];
    const float* bv = (const float*)d_in[7];
    float* out = (float*)d_out;

    char* ws = (char*)d_ws;                                  // needs 278784 B
    unsigned short* GFh = (unsigned short*)(ws);             // 8192 B
    unsigned short* GFl = (unsigned short*)(ws + 8192);      // 8192 B
    float*          uW  = (float*)(ws + 16384);              // 256 B
    unsigned short* KF  = (unsigned short*)(ws + 16640);     // 131072 B
    unsigned short* VF  = (unsigned short*)(ws + 147712);    // 131072 B (end 278784)

    prep_kernel<<<33, 256, 0, stream>>>(nb, Wq, bq, Wk, GFh, GFl, uW, KF, VF);
    const int grid = (N_ROWS + 63) / 64;   // 1563 1-wave blocks, 64 rows each
    attn_kernel<<<grid, 64, 0, stream>>>(x, GFh, GFl, uW, KF, VF, Wv, bv, out);
}

// Round 10
// 146.734 us; speedup vs baseline: 1.1018x; 1.0305x over previous
//
#include <hip/hip_runtime.h>

// RelationGAT fused flash-attention, MFMA fp16 (gfx950) -- R16 "R10 base + setprio + VALU trims".
// out = softmax((x@Wq^T+bq) @ (nb@Wk^T+bk)^T) @ nb @ Wv^T + bv
// bk cancels in softmax. Q~ = x@G + u, G = Wq^T Wk, u = bq^T Wk; K=V=raw nb.
//
// R16 theory: R15 killed the loads-per-work law (75.5 vs predicted 48-62).
// 9 structural variants pin time at 74-76us; per-wave wall ~2850cyc/step vs
// ~500cyc accounted content; MfmaUtil back-computation (16cyc/MFMA vs 4.85
// ubench) says the derived counters are unreliable here. Last lever with
// measured precedent in THIS regime (many independent 1-wave blocks/CU):
// T5 s_setprio(1) around MFMA clusters (+4-7% attn, m191). Base = R10's
// best-measured schedule (74.0us: K dbuf one full step ahead, V reload
// post-PV, ~3/4-step slack) + the R14b-verified VALU trims (exp2 domain,
// cvt_pkrtz pack, tree-sum). PRE-COMMIT: null (>=74) => practical plateau.
//
// Workspace layout (278784 B):
//   [0,8192)         GFh  fp16 frag-major G^T hi: [f=mt*2+ks][lane][8]
//   [8192,16384)     GFl  fp16 frag-major G^T lo
//   [16384,16640)    uW   f32 [64]
//   [16640,147712)   KF   fp16 [tile][f=t*2+h][lane][8], key-permuted
//   [147712,278784)  VF   fp16 [tile][dt][lane][8], natural key order

#define N_ROWS 100000
#define LOG2E 1.44269504088896f
#define GATE_THR 11.5424f   // 8 nats in log2 units; p <= 2^11.54 ~ 2981 fits fp16

typedef __attribute__((ext_vector_type(8))) _Float16 half8;
typedef __attribute__((ext_vector_type(2))) __fp16   fp16x2;   // cvt_pkrtz return type
typedef __attribute__((ext_vector_type(4))) float    f32x4;

#define MFMA16(a,b,c) __builtin_amdgcn_mfma_f32_16x16x32_f16((a),(b),(c),0,0,0)

static __device__ __forceinline__ f32x4 zero4() {
    f32x4 v = {0.f, 0.f, 0.f, 0.f};
    return v;
}

// ---------------- prep: GF hi/lo + u (block 0), nb -> KF/VF fp16 (blocks 1..32) ----------------
__global__ __launch_bounds__(256)
void prep_kernel(const float* __restrict__ nb, const float* __restrict__ Wq,
                 const float* __restrict__ bq, const float* __restrict__ Wk,
                 unsigned short* __restrict__ GFh, unsigned short* __restrict__ GFl,
                 float* __restrict__ uW, unsigned short* __restrict__ KF,
                 unsigned short* __restrict__ VF)
{
    __shared__ __align__(16) float sm[8192];   // 32KB: blk0 Wk|Wq, blks>0 transpose tile
    const int tid = threadIdx.x;
    if (blockIdx.x == 0) {
        const float4* wk4 = (const float4*)Wk;
        const float4* wq4 = (const float4*)Wq;
        float4* dk = (float4*)sm;
        float4* dq = (float4*)(sm + 4096);
        #pragma unroll
        for (int u = 0; u < 4; u++) {
            dk[u * 256 + tid] = wk4[u * 256 + tid];
            dq[u * 256 + tid] = wq4[u * 256 + tid];
        }
        __syncthreads();
        const int e2 = tid & 63, e1g = (tid >> 6) * 16;
        float g[16];
        #pragma unroll
        for (int q = 0; q < 16; q++) g[q] = 0.f;
        for (int w = 0; w < 64; w++) {
            float kv = sm[w * 64 + e2];
            const float* wqp = sm + 4096 + w * 64 + e1g;
            #pragma unroll
            for (int q = 0; q < 16; q++) g[q] = fmaf(wqp[q], kv, g[q]);
        }
        union { half8 h; uint4 u; } ph0, pl0, ph1, pl1;
        #pragma unroll
        for (int i = 0; i < 8; i++) {
            _Float16 h0 = (_Float16)g[i];
            ph0.h[i] = h0; pl0.h[i] = (_Float16)(g[i] - (float)h0);
            _Float16 h1 = (_Float16)g[8 + i];
            ph1.h[i] = h1; pl1.h[i] = (_Float16)(g[8 + i] - (float)h1);
        }
        // frag-major: f = mt*2+ks, lane = Q*16+c ; this thread owns row e2 ->
        // (mt = e2>>4, c = e2&15), cols e1g..e1g+15 -> ks = tid>>7, Q0 = 2*((tid>>6)&1)
        const int mt = e2 >> 4, cc = e2 & 15;
        const int ks = tid >> 7, Q0 = 2 * ((tid >> 6) & 1);
        const int f  = mt * 2 + ks;
        *(uint4*)(GFh + (f * 64 + Q0 * 16 + cc) * 8)       = ph0.u;
        *(uint4*)(GFh + (f * 64 + (Q0 + 1) * 16 + cc) * 8) = ph1.u;
        *(uint4*)(GFl + (f * 64 + Q0 * 16 + cc) * 8)       = pl0.u;
        *(uint4*)(GFl + (f * 64 + (Q0 + 1) * 16 + cc) * 8) = pl1.u;
        if (tid < 64) {
            float uu = 0.f;
            for (int w = 0; w < 64; w++) uu = fmaf(bq[w], sm[w * 64 + tid], uu);
            uW[tid] = uu;
        }
    } else {
        const int T0 = blockIdx.x - 1;   // this block's 32-key tile
        const int j0 = T0 * 32;
        // stage 32x64 f32 tile to LDS [32][65] for the VF transpose
        {
            const int jr = tid >> 3, c0 = (tid & 7) * 8;
            const float* np = nb + (size_t)(j0 + jr) * 64 + c0;
            float4 v0 = *(const float4*)np;
            float4 v1 = *(const float4*)(np + 4);
            sm[jr * 65 + c0 + 0] = v0.x; sm[jr * 65 + c0 + 1] = v0.y;
            sm[jr * 65 + c0 + 2] = v0.z; sm[jr * 65 + c0 + 3] = v0.w;
            sm[jr * 65 + c0 + 4] = v1.x; sm[jr * 65 + c0 + 5] = v1.y;
            sm[jr * 65 + c0 + 6] = v1.z; sm[jr * 65 + c0 + 7] = v1.w;
        }
        // KF direct from global: tid -> (f=(t,h), lane=(Q,c)); stored key row is the
        // PERMUTED key keyof(t,c) so that S-frag reg r at lane(Q,c) = key 8Q+4t+r.
        {
            const int f = tid >> 6, ln = tid & 63;
            const int t = f >> 1, h = f & 1, Qw = ln >> 4, cw = ln & 15;
            const int key = ((cw >> 3) & 1) * 16 + ((cw >> 2) & 1) * 8 + 4 * t + (cw & 3);
            const float* kp = nb + (size_t)(j0 + key) * 64 + h * 32 + Qw * 8;
            float b[8];
            *(float4*)b       = *(const float4*)kp;
            *(float4*)(b + 4) = *(const float4*)(kp + 4);
            union { half8 hh; uint4 u; } pk;
            #pragma unroll
            for (int i = 0; i < 8; i++) pk.hh[i] = (_Float16)b[i];
            *(uint4*)(KF + (size_t)T0 * 2048 + f * 512 + ln * 8) = pk.u;
        }
        __syncthreads();
        // VF from LDS transpose: VF[T0][dt][lane(Q,c)][i] = nb[j0 + Q*8 + i][dt*16+c]
        {
            const int dt = tid >> 6, ln = tid & 63;
            const int Qw = ln >> 4, cw = ln & 15;
            union { half8 hh; uint4 u; } pv;
            #pragma unroll
            for (int i = 0; i < 8; i++)
                pv.hh[i] = (_Float16)sm[(Qw * 8 + i) * 65 + dt * 16 + cw];
            *(uint4*)(VF + (size_t)T0 * 2048 + dt * 512 + ln * 8) = pv.u;
        }
    }
}

// One 32-key flash step: compute with ck/vA, prefetch K[Tn] into nk, reload vA <- V[Tn]
// at the end (WAR after PV issue; ~3/4-step slack). MFMA clusters wrapped in setprio (T5).
static __device__ __forceinline__ void flash_step(
    const unsigned short* __restrict__ kfl, const unsigned short* __restrict__ vfl,
    int Tn,
    const half8 (&ck)[4], half8 (&nk)[4], half8 (&vA)[4],
    const half8 (&qh)[2][2], const half8 (&ql)[2][2],
    f32x4 (&acc)[2][4], float (&mrow)[2], float (&lrow)[2])
{
    // prefetch next tile's K frags -- contiguous 1KB per instr, imm offsets
    const unsigned short* kn = kfl + (size_t)Tn * 2048;
    #pragma unroll
    for (int f = 0; f < 4; f++) nk[f] = *(const half8*)(kn + f * 512);

    // S tiles (log2-scaled); key of S-frag lane(Q,c) reg r = T*32 + 8Q + 4t + r
    f32x4 S[2][2];   // [t][qt]
    __builtin_amdgcn_s_setprio(1);
    #pragma unroll
    for (int t = 0; t < 2; t++)
        #pragma unroll
        for (int qt = 0; qt < 2; qt++) {
            f32x4 s = MFMA16(ck[2 * t],     qh[qt][0], zero4());
            s = MFMA16(ck[2 * t + 1], qh[qt][1], s);
            s = MFMA16(ck[2 * t],     ql[qt][0], s);
            s = MFMA16(ck[2 * t + 1], ql[qt][1], s);
            S[t][qt] = s;
        }
    __builtin_amdgcn_s_setprio(0);

    float pmax[2];
    #pragma unroll
    for (int qt = 0; qt < 2; qt++) {
        pmax[qt] = fmaxf(fmaxf(fmaxf(S[0][qt][0], S[0][qt][1]),
                               fmaxf(S[0][qt][2], S[0][qt][3])),
                         fmaxf(fmaxf(S[1][qt][0], S[1][qt][1]),
                               fmaxf(S[1][qt][2], S[1][qt][3])));
    }
    // defer-max (T13): wave-uniform gate via __any (VOPC+exec, zero DS ops)
    if (__any((pmax[0] > mrow[0] + GATE_THR) | (pmax[1] > mrow[1] + GATE_THR))) {
        #pragma unroll
        for (int qt = 0; qt < 2; qt++) {
            float cm = pmax[qt];
            cm = fmaxf(cm, __shfl_xor(cm, 16));
            cm = fmaxf(cm, __shfl_xor(cm, 32));   // uniform per q-row c across quads
            const float mn = fmaxf(mrow[qt], cm);
            const float sc = __builtin_amdgcn_exp2f(mrow[qt] - mn);
            mrow[qt] = mn;
            lrow[qt] *= sc;
            #pragma unroll
            for (int dt = 0; dt < 4; dt++)
                #pragma unroll
                for (int r = 0; r < 4; r++) acc[qt][dt][r] *= sc;
        }
    }
    union { half8 v; fp16x2 h2[4]; } pk[2];
    #pragma unroll
    for (int qt = 0; qt < 2; qt++) {
        const float mref = mrow[qt];
        float p[8];
        #pragma unroll
        for (int r = 0; r < 4; r++) {
            p[r]     = __builtin_amdgcn_exp2f(S[0][qt][r] - mref);
            p[4 + r] = __builtin_amdgcn_exp2f(S[1][qt][r] - mref);
        }
        // tree sum (depth 3, not a serial 8-chain); per-lane PARTIAL, reduced in epilogue
        lrow[qt] += ((p[0] + p[1]) + (p[2] + p[3])) + ((p[4] + p[5]) + (p[6] + p[7]));
        // pack pairs f32->fp16 in one v_cvt_pkrtz each; order matches PV B-frag
        #pragma unroll
        for (int j = 0; j < 4; j++)
            pk[qt].h2[j] = __builtin_amdgcn_cvt_pkrtz(p[2 * j], p[2 * j + 1]);
    }
    __builtin_amdgcn_s_setprio(1);
    #pragma unroll
    for (int dt = 0; dt < 4; dt++) {
        acc[0][dt] = MFMA16(vA[dt], pk[0].v, acc[0][dt]);
        acc[1][dt] = MFMA16(vA[dt], pk[1].v, acc[1][dt]);
    }
    __builtin_amdgcn_s_setprio(0);
    // reload vA in-place from next tile (WAR after PV issue; ~3/4-step latency budget)
    const unsigned short* vn = vfl + (size_t)Tn * 2048;
    #pragma unroll
    for (int d = 0; d < 4; d++) vA[d] = *(const half8*)(vn + d * 512);
}

// ---------------- main: 1-wave blocks, 32 rows/wave, barrier-free, frag-major K/V ----------------
__global__ __launch_bounds__(64, 3)
void attn_kernel(const float* __restrict__ x,
                 const unsigned short* __restrict__ GFh,
                 const unsigned short* __restrict__ GFl,
                 const float* __restrict__ uW,
                 const unsigned short* __restrict__ KF,
                 const unsigned short* __restrict__ VF,
                 const float* __restrict__ Wv,
                 const float* __restrict__ bv,
                 float* __restrict__ out)
{
    __shared__ __align__(16) float slice[1088];   // [16][68] f32 Q-transpose slice (wave-private)
    const int lane = threadIdx.x & 63;
    const int Q    = lane >> 4;    // quad 0..3
    const int c    = lane & 15;    // col 0..15
    const int rbase = blockIdx.x * 32;   // this wave's 32 q-rows (3125*32 = 100000 exactly)

    // ------- setup: Q~^T = G^T x^T via MFMA (frag-major G from L2) -> q-frags hi/lo -------
    // log2(e) folded into Q~ before the hi/lo split -> scores come out log2-scaled.
    half8 qh[2][2], ql[2][2];   // [rt][ks] -- static indices ONLY
    #pragma unroll
    for (int rt = 0; rt < 2; rt++) {
        const int row = rbase + rt * 16 + c;   // always < N_ROWS (exact tiling)
        half8 xh[2], xl[2];
        #pragma unroll
        for (int ks = 0; ks < 2; ks++) {
            const float* xp = x + (size_t)row * 64 + ks * 32 + Q * 8;
            float a[8];
            *(float4*)a       = *(const float4*)xp;
            *(float4*)(a + 4) = *(const float4*)(xp + 4);
            #pragma unroll
            for (int i = 0; i < 8; i++) {
                _Float16 h = (_Float16)a[i];
                xh[ks][i] = h;
                xl[ks][i] = (_Float16)(a[i] - (float)h);
            }
        }
        #pragma unroll
        for (int mt = 0; mt < 4; mt++) {
            f32x4 Cm = zero4();
            #pragma unroll
            for (int ks = 0; ks < 2; ks++) {
                half8 gh = *(const half8*)(GFh + ((mt * 2 + ks) * 64 + lane) * 8);
                half8 gl = *(const half8*)(GFl + ((mt * 2 + ks) * 64 + lane) * 8);
                Cm = MFMA16(gh, xh[ks], Cm);   // D[dout][x-row]
                Cm = MFMA16(gh, xl[ks], Cm);
                Cm = MFMA16(gl, xh[ks], Cm);
            }
            // C row = dout mt*16+4Q+r, col = x-row c -> slice[x-row][dout]
            *(f32x4*)(slice + c * 68 + mt * 16 + 4 * Q) = Cm;
        }
        __builtin_amdgcn_s_waitcnt(0);   // wave-local LDS RAW (slice is wave-private)
        #pragma unroll
        for (int ks = 0; ks < 2; ks++) {
            const float* qp = slice + c * 68 + ks * 32 + Q * 8;
            const float* up = uW + ks * 32 + Q * 8;
            #pragma unroll
            for (int i = 0; i < 8; i++) {
                float val = (qp[i] + up[i]) * LOG2E;
                _Float16 h = (_Float16)val;
                qh[rt][ks][i] = h;
                ql[rt][ks][i] = (_Float16)(val - (float)h);
            }
        }
        __builtin_amdgcn_s_waitcnt(0);   // reads done before rt=1 overwrites slice
    }

    // ---------------- flash loop: 32 tiles of 32 keys, K dbuf + V in-place prefetch ----------------
    f32x4 acc[2][4];   // [qt][dt] agg^T C-frags (static idx only)
    #pragma unroll
    for (int qt = 0; qt < 2; qt++)
        #pragma unroll
        for (int dt = 0; dt < 4; dt++) acc[qt][dt] = zero4();
    float mrow[2] = { -3.0e38f, -3.0e38f };
    float lrow[2] = { 0.f, 0.f };

    const unsigned short* kfl = KF + lane * 8;   // per-lane frag base (ushort units)
    const unsigned short* vfl = VF + lane * 8;
    half8 kA[4], kB[4], vA[4];
    #pragma unroll
    for (int f = 0; f < 4; f++) kA[f] = *(const half8*)(kfl + f * 512);   // tile 0 K
    #pragma unroll
    for (int d = 0; d < 4; d++) vA[d] = *(const half8*)(vfl + d * 512);   // tile 0 V

    #pragma unroll 1
    for (int TT = 0; TT < 16; TT++) {
        flash_step(kfl, vfl, 2 * TT + 1, kA, kB, vA, qh, ql, acc, mrow, lrow);
        const int Tn = (2 * TT + 2 < 32) ? 2 * TT + 2 : 31;   // clamp last prefetch
        flash_step(kfl, vfl, Tn,         kB, kA, vA, qh, ql, acc, mrow, lrow);
    }

    // ---------------- epilogue: reduce lrow partials, out = (agg/l) @ Wv^T + bv ----------------
    #pragma unroll
    for (int qt = 0; qt < 2; qt++) {
        float l = lrow[qt];
        l += __shfl_xor(l, 16);
        l += __shfl_xor(l, 32);     // once per kernel, not per iter
        const float rl = 1.f / l;
        #pragma unroll
        for (int dt = 0; dt < 4; dt++)
            #pragma unroll
            for (int r = 0; r < 4; r++) acc[qt][dt][r] *= rl;
    }
    half8 wf[4][2];
    #pragma unroll
    for (int mt = 0; mt < 4; mt++)
        #pragma unroll
        for (int ks = 0; ks < 2; ks++) {
            const float* wp = Wv + (size_t)(mt * 16 + c) * 64 + ks * 32 + Q * 8;
            #pragma unroll
            for (int i = 0; i < 8; i++) wf[mt][ks][i] = (_Float16)wp[i];
        }
    const int srcA = 32 * (Q & 1) + c;
    const int srcB = srcA + 16;
    const bool hi = (Q >> 1) & 1;
    f32x4 o[2][4];
    #pragma unroll
    for (int qt = 0; qt < 2; qt++) {
        half8 pe[2];
        #pragma unroll
        for (int ks = 0; ks < 2; ks++) {
            #pragma unroll
            for (int r = 0; r < 4; r++) {
                float a0 = __shfl(acc[qt][2 * ks + 0][r], srcA);
                float a1 = __shfl(acc[qt][2 * ks + 1][r], srcA);
                float b0 = __shfl(acc[qt][2 * ks + 0][r], srcB);
                float b1 = __shfl(acc[qt][2 * ks + 1][r], srcB);
                pe[ks][r]     = (_Float16)(hi ? a1 : a0);
                pe[ks][4 + r] = (_Float16)(hi ? b1 : b0);
            }
        }
        #pragma unroll
        for (int mt = 0; mt < 4; mt++) {
            f32x4 t = MFMA16(wf[mt][0], pe[0], zero4());
            o[qt][mt] = MFMA16(wf[mt][1], pe[1], t);
        }
    }
    #pragma unroll
    for (int qt = 0; qt < 2; qt++) {
        const int row = rbase + qt * 16 + c;   // always < N_ROWS (exact tiling)
        #pragma unroll
        for (int mt = 0; mt < 4; mt++) {
            const float4 bf = *(const float4*)(bv + mt * 16 + 4 * Q);
            float4 vv = make_float4(o[qt][mt][0] + bf.x, o[qt][mt][1] + bf.y,
                                    o[qt][mt][2] + bf.z, o[qt][mt][3] + bf.w);
            *(float4*)(out + (size_t)row * 64 + mt * 16 + 4 * Q) = vv;
        }
    }
}

extern "C" void kernel_launch(void* const* d_in, const int* in_sizes, int n_in,
                              void* d_out, int out_size, void* d_ws, size_t ws_size,
                              hipStream_t stream)
{
    const float* x  = (const float*)d_in[0];
    const float* nb = (const float*)d_in[1];
    const float* Wq = (const float*)d_in[2];
    const float* bq = (const float*)d_in[3];
    const float* Wk = (const float*)d_in[4];
    // d_in[5] = bk: provably cancels in softmax -> unused
    const float* Wv = (const float*)d_in[6];
    const float* bv = (const float*)d_in[7];
    float* out = (float*)d_out;

    char* ws = (char*)d_ws;                                  // needs 278784 B
    unsigned short* GFh = (unsigned short*)(ws);             // 8192 B
    unsigned short* GFl = (unsigned short*)(ws + 8192);      // 8192 B
    float*          uW  = (float*)(ws + 16384);              // 256 B
    unsigned short* KF  = (unsigned short*)(ws + 16640);     // 131072 B
    unsigned short* VF  = (unsigned short*)(ws + 147712);    // 131072 B (end 278784)

    prep_kernel<<<33, 256, 0, stream>>>(nb, Wq, bq, Wk, GFh, GFl, uW, KF, VF);
    const int grid = N_ROWS / 32;   // 3125 1-wave blocks, 32 rows each, zero padding
    attn_kernel<<<grid, 64, 0, stream>>>(x, GFh, GFl, uW, KF, VF, Wv, bv, out);
}